// Round 1
// baseline (319.111 us; speedup 1.0000x reference)
//
#include <hip/hip_runtime.h>

#define B_NUM 4
#define S_DIM 2048
#define D_DIM 1024
#define O_DIM 1024
#define E_NUM 16
#define K_SEL 512

typedef __attribute__((ext_vector_type(4))) float f32x4;
typedef __attribute__((ext_vector_type(8))) short s16x8;

__device__ __forceinline__ unsigned short f2b(float f) {
  union { float f; unsigned int u; } c; c.f = f;
  unsigned int u = c.u;
  u += 0x7fffu + ((u >> 16) & 1u);   // RNE to bf16
  return (unsigned short)(u >> 16);
}

// ---------------- x fp32 -> bf16 (same layout) ----------------
__global__ void convert_x_kernel(const float* __restrict__ x, unsigned short* __restrict__ xb) {
  int i = blockIdx.x * blockDim.x + threadIdx.x;  // one float4 each; grid sized exactly
  float4 v = reinterpret_cast<const float4*>(x)[i];
  ushort4 u;
  u.x = f2b(v.x); u.y = f2b(v.y); u.z = f2b(v.z); u.w = f2b(v.w);
  reinterpret_cast<ushort4*>(xb)[i] = u;
}

// ---------------- w[e][d][o] fp32 -> wT[e][o][d] bf16 ----------------
__global__ void transpose_w_kernel(const float* __restrict__ w, unsigned short* __restrict__ wt) {
  __shared__ float tile[32][33];
  int e = blockIdx.z;
  int d0 = blockIdx.y * 32, o0 = blockIdx.x * 32;
  const float* wbase = w + (size_t)e * D_DIM * O_DIM;
  for (int r = threadIdx.y; r < 32; r += 8)
    tile[r][threadIdx.x] = wbase[(size_t)(d0 + r) * O_DIM + o0 + threadIdx.x];
  __syncthreads();
  unsigned short* wtb = wt + (size_t)e * O_DIM * D_DIM;
  for (int r = threadIdx.y; r < 32; r += 8)
    wtb[(size_t)(o0 + r) * D_DIM + d0 + threadIdx.x] = f2b(tile[threadIdx.x][r]);
}

// ---------------- gate logits: logits_t[b][e][s] = x[b,s,:]@gate_w[:,e] + gate_b[e] (fp32) ----------------
__global__ void gate_kernel(const float* __restrict__ x, const float* __restrict__ gw,
                            const float* __restrict__ gb, float* __restrict__ logits_t) {
  int wave = (blockIdx.x * blockDim.x + threadIdx.x) >> 6;  // token index, exact grid
  int ln = threadIdx.x & 63;
  int bi = wave / S_DIM, s = wave % S_DIM;
  const float* xr = x + (size_t)wave * D_DIM;
  float acc[E_NUM];
#pragma unroll
  for (int e = 0; e < E_NUM; ++e) acc[e] = 0.f;
  for (int it = 0; it < D_DIM / 64; ++it) {
    int d = it * 64 + ln;
    float xv = xr[d];
    const float* g = gw + (size_t)d * E_NUM;
#pragma unroll
    for (int e = 0; e < E_NUM; ++e) acc[e] = fmaf(xv, g[e], acc[e]);
  }
  float myv = 0.f;
#pragma unroll
  for (int e = 0; e < E_NUM; ++e) {
    float v = acc[e];
#pragma unroll
    for (int o = 32; o > 0; o >>= 1) v += __shfl_xor(v, o);
    if (ln == e) myv = v;
  }
  if (ln < E_NUM)
    logits_t[((size_t)bi * E_NUM + ln) * S_DIM + s] = myv + gb[ln];
}

// ---------------- per-(b,e): softmax over S, bitonic sort (p desc, idx asc), emit top-K ----------------
__global__ __launch_bounds__(256) void topk_kernel(const float* __restrict__ logits_t,
                                                   float* __restrict__ vals, int* __restrict__ idxb) {
  __shared__ float sv[S_DIM];
  __shared__ int si[S_DIM];
  __shared__ float red[256];
  int row = blockIdx.x;  // b*E + e
  int tid = threadIdx.x;
  const float* lp = logits_t + (size_t)row * S_DIM;

  float lmax = -1e30f;
  for (int s = tid; s < S_DIM; s += 256) {
    float v = lp[s];
    sv[s] = v; si[s] = s;
    lmax = fmaxf(lmax, v);
  }
  red[tid] = lmax; __syncthreads();
  for (int o = 128; o > 0; o >>= 1) {
    if (tid < o) red[tid] = fmaxf(red[tid], red[tid + o]);
    __syncthreads();
  }
  float mx = red[0]; __syncthreads();

  float lsum = 0.f;
  for (int s = tid; s < S_DIM; s += 256) lsum += expf(sv[s] - mx);
  red[tid] = lsum; __syncthreads();
  for (int o = 128; o > 0; o >>= 1) {
    if (tid < o) red[tid] += red[tid + o];
    __syncthreads();
  }
  float Z = red[0]; __syncthreads();

  for (int s = tid; s < S_DIM; s += 256) sv[s] = expf(sv[s] - mx) / Z;

  // bitonic sort: final order = (prob desc, idx asc). Total order (idx unique).
  for (int k = 2; k <= S_DIM; k <<= 1) {
    for (int j = k >> 1; j > 0; j >>= 1) {
      __syncthreads();
      for (int i = tid; i < S_DIM; i += 256) {
        int ixj = i ^ j;
        if (ixj > i) {
          float va = sv[i], vb = sv[ixj];
          int ia = si[i], ib = si[ixj];
          bool a_first = (va > vb) || (va == vb && ia < ib);
          bool up = ((i & k) == 0);
          if (up != a_first) {
            sv[i] = vb; sv[ixj] = va;
            si[i] = ib; si[ixj] = ia;
          }
        }
      }
    }
  }
  __syncthreads();
  for (int t = tid; t < K_SEL; t += 256) {
    vals[(size_t)row * K_SEL + t] = sv[t];
    idxb[(size_t)row * K_SEL + t] = si[t];
  }
}

// ---------------- grouped GEMM: per (b,e): C[k,o] = gather(x)[k,:] @ w[e], epilogue scatter ----------------
// 128x128 tile, BK=64, 4 waves (2x2), mfma_f32_16x16x32_bf16, global_load_lds w16,
// XOR slot-swizzle (phys_slot = logical_slot ^ (row&7)) applied on the GLOBAL SOURCE (linear LDS dest)
// and on the LDS frag reads.
__global__ __launch_bounds__(256) void moe_gemm_kernel(
    const unsigned short* __restrict__ xb,   // [B,S,D] bf16
    const unsigned short* __restrict__ wt,   // [E,O,D] bf16
    const int* __restrict__ idxbuf,          // [B*E,K]
    const float* __restrict__ valbuf,        // [B*E,K]
    const float* __restrict__ bias,          // [E]
    float* __restrict__ out)                 // [B,S,O] fp32
{
  __shared__ __align__(16) unsigned short lA[128 * 64];
  __shared__ __align__(16) unsigned short lB[128 * 64];

  const int tid = threadIdx.x;
  const int wv = tid >> 6, ln = tid & 63;
  const int grp = blockIdx.z;            // b*E + e
  const int bi = grp >> 4, ei = grp & 15;
  const int m0 = blockIdx.y * 128;       // token-slot tile base (within K_SEL)
  const int n0 = blockIdx.x * 128;       // output-col tile base
  const int wm = wv >> 1, wn = wv & 1;   // wave 64x64 sub-tile

  // per-thread staging sources (4 ld-insts per operand per K-step)
  const unsigned short* aSrc[4];
  const unsigned short* bSrc[4];
#pragma unroll
  for (int t = 0; t < 4; ++t) {
    int row = t * 32 + (tid >> 3);            // 0..127 within tile
    int lslot = (tid & 7) ^ (row & 7);        // inverse-swizzled source slot
    int tok = idxbuf[grp * K_SEL + m0 + row];
    aSrc[t] = xb + ((size_t)bi * S_DIM + tok) * D_DIM + lslot * 8;
    int oc = n0 + row;
    bSrc[t] = wt + ((size_t)ei * O_DIM + oc) * D_DIM + lslot * 8;
  }

  f32x4 acc[4][4];
  f32x4 zero4 = {0.f, 0.f, 0.f, 0.f};
#pragma unroll
  for (int i = 0; i < 4; ++i)
#pragma unroll
    for (int j = 0; j < 4; ++j) acc[i][j] = zero4;

  for (int kt = 0; kt < D_DIM / 64; ++kt) {
    __syncthreads();
#pragma unroll
    for (int t = 0; t < 4; ++t) {
      __builtin_amdgcn_global_load_lds(
          (const __attribute__((address_space(1))) void*)(aSrc[t] + kt * 64),
          (__attribute__((address_space(3))) void*)(&lA[t * 2048 + wv * 512]), 16, 0, 0);
      __builtin_amdgcn_global_load_lds(
          (const __attribute__((address_space(1))) void*)(bSrc[t] + kt * 64),
          (__attribute__((address_space(3))) void*)(&lB[t * 2048 + wv * 512]), 16, 0, 0);
    }
    __syncthreads();

#pragma unroll
    for (int ks = 0; ks < 2; ++ks) {
      s16x8 af[4], bfr[4];
#pragma unroll
      for (int i = 0; i < 4; ++i) {
        int row = wm * 64 + i * 16 + (ln & 15);
        int slot = (ks * 4 + (ln >> 4)) ^ (row & 7);
        af[i] = *(const s16x8*)&lA[row * 64 + slot * 8];
      }
#pragma unroll
      for (int j = 0; j < 4; ++j) {
        int row = wn * 64 + j * 16 + (ln & 15);
        int slot = (ks * 4 + (ln >> 4)) ^ (row & 7);
        bfr[j] = *(const s16x8*)&lB[row * 64 + slot * 8];
      }
#pragma unroll
      for (int i = 0; i < 4; ++i)
#pragma unroll
        for (int j = 0; j < 4; ++j)
          acc[i][j] = __builtin_amdgcn_mfma_f32_16x16x32_bf16(af[i], bfr[j], acc[i][j], 0, 0, 0);
    }
  }

  // epilogue: (acc + b[e]) / val, atomic scatter-add to out[b, idx, col]
  const float be = bias[ei];
#pragma unroll
  for (int i = 0; i < 4; ++i) {
#pragma unroll
    for (int r = 0; r < 4; ++r) {
      int krow = m0 + wm * 64 + i * 16 + (ln >> 4) * 4 + r;
      int tok = idxbuf[grp * K_SEL + krow];
      float vv = valbuf[grp * K_SEL + krow];
      float* orow = out + ((size_t)bi * S_DIM + tok) * O_DIM;
#pragma unroll
      for (int j = 0; j < 4; ++j) {
        int col = n0 + wn * 64 + j * 16 + (ln & 15);
        atomicAdd(&orow[col], (acc[i][j][r] + be) / vv);
      }
    }
  }
}

extern "C" void kernel_launch(void* const* d_in, const int* in_sizes, int n_in,
                              void* d_out, int out_size, void* d_ws, size_t ws_size,
                              hipStream_t stream) {
  const float* x   = (const float*)d_in[0];
  const float* gw  = (const float*)d_in[1];
  const float* gb  = (const float*)d_in[2];
  const float* w   = (const float*)d_in[3];
  const float* bia = (const float*)d_in[4];
  float* out = (float*)d_out;

  char* ws = (char*)d_ws;
  float*          logits_t = (float*)ws;                                   // 512 KB
  float*          vals     = (float*)(ws + 524288);                        // 128 KB
  int*            idxb     = (int*)(ws + 655360);                          // 128 KB
  unsigned short* xbf      = (unsigned short*)(ws + 786432);               // 16 MB
  unsigned short* wtb      = (unsigned short*)(ws + 786432 + 16777216);    // 32 MB

  hipMemsetAsync(d_out, 0, (size_t)out_size * sizeof(float), stream);

  convert_x_kernel<<<dim3((B_NUM * S_DIM * D_DIM) / 4 / 256), dim3(256), 0, stream>>>(x, xbf);
  transpose_w_kernel<<<dim3(O_DIM / 32, D_DIM / 32, E_NUM), dim3(32, 8), 0, stream>>>(w, wtb);
  gate_kernel<<<dim3((B_NUM * S_DIM) / 4), dim3(256), 0, stream>>>(x, gw, gb, logits_t);
  topk_kernel<<<dim3(B_NUM * E_NUM), dim3(256), 0, stream>>>(logits_t, vals, idxb);
  moe_gemm_kernel<<<dim3(O_DIM / 128, K_SEL / 128, B_NUM * E_NUM), dim3(256), 0, stream>>>(
      xbf, wtb, idxb, vals, bia, out);
}

// Round 2
// 284.659 us; speedup vs baseline: 1.1210x; 1.1210x over previous
//
#include <hip/hip_runtime.h>

#define B_NUM 4
#define S_DIM 2048
#define D_DIM 1024
#define O_DIM 1024
#define E_NUM 16
#define K_SEL 512

typedef __attribute__((ext_vector_type(4))) float f32x4;
typedef __attribute__((ext_vector_type(8))) short s16x8;

__device__ __forceinline__ unsigned short f2b(float f) {
  union { float f; unsigned int u; } c; c.f = f;
  unsigned int u = c.u;
  u += 0x7fffu + ((u >> 16) & 1u);   // RNE to bf16
  return (unsigned short)(u >> 16);
}

// ---------------- gate + x-convert fused ----------------
// one wave per token: fp32 gate logits (exact top-k ordering), bf16 x emitted.
__global__ __launch_bounds__(256) void gate_kernel(const float* __restrict__ x,
                                                   const float* __restrict__ gw,
                                                   const float* __restrict__ gb,
                                                   float* __restrict__ logits_t,
                                                   unsigned short* __restrict__ xb) {
  int wave = (blockIdx.x * blockDim.x + threadIdx.x) >> 6;  // token index
  int ln = threadIdx.x & 63;
  int bi = wave / S_DIM, s = wave % S_DIM;
  const float* xr = x + (size_t)wave * D_DIM;
  unsigned short* xbr = xb + (size_t)wave * D_DIM;
  float acc[E_NUM];
#pragma unroll
  for (int e = 0; e < E_NUM; ++e) acc[e] = 0.f;
#pragma unroll
  for (int it = 0; it < 4; ++it) {
    int d0 = it * 256 + ln * 4;
    float4 xv = *reinterpret_cast<const float4*>(&xr[d0]);
    ushort4 u;
    u.x = f2b(xv.x); u.y = f2b(xv.y); u.z = f2b(xv.z); u.w = f2b(xv.w);
    *reinterpret_cast<ushort4*>(&xbr[d0]) = u;
    const float* g = gw + (size_t)d0 * E_NUM;
#pragma unroll
    for (int e = 0; e < E_NUM; ++e)
      acc[e] = fmaf(xv.x, g[e], fmaf(xv.y, g[E_NUM + e],
               fmaf(xv.z, g[2 * E_NUM + e], fmaf(xv.w, g[3 * E_NUM + e], acc[e]))));
  }
  float myv = 0.f;
#pragma unroll
  for (int e = 0; e < E_NUM; ++e) {
    float v = acc[e];
#pragma unroll
    for (int o = 32; o > 0; o >>= 1) v += __shfl_xor(v, o);
    if (ln == e) myv = v;
  }
  if (ln < E_NUM)
    logits_t[((size_t)bi * E_NUM + ln) * S_DIM + s] = myv + gb[ln];
}

// ---------------- w[e][d][o] fp32 -> wT[e][o][d] bf16, 64x64 tiles ----------------
__global__ __launch_bounds__(256) void transpose_w_kernel(const float* __restrict__ w,
                                                          unsigned short* __restrict__ wt) {
  __shared__ float tile[64][65];
  int e = blockIdx.z;
  int d0 = blockIdx.y * 64, o0 = blockIdx.x * 64;
  int tx = threadIdx.x & 15, ty = threadIdx.x >> 4;  // tx: float4 col, ty: row
  const float* wbase = w + (size_t)e * D_DIM * O_DIM;
#pragma unroll
  for (int r = 0; r < 4; ++r) {
    int row = r * 16 + ty;
    float4 v = *reinterpret_cast<const float4*>(&wbase[(size_t)(d0 + row) * O_DIM + o0 + tx * 4]);
    tile[row][tx * 4 + 0] = v.x; tile[row][tx * 4 + 1] = v.y;
    tile[row][tx * 4 + 2] = v.z; tile[row][tx * 4 + 3] = v.w;
  }
  __syncthreads();
  unsigned short* wtb = wt + (size_t)e * O_DIM * D_DIM;
#pragma unroll
  for (int r = 0; r < 4; ++r) {
    int orow = r * 16 + ty;
    ushort4 u;
    u.x = f2b(tile[tx * 4 + 0][orow]);
    u.y = f2b(tile[tx * 4 + 1][orow]);
    u.z = f2b(tile[tx * 4 + 2][orow]);
    u.w = f2b(tile[tx * 4 + 3][orow]);
    *reinterpret_cast<ushort4*>(&wtb[(size_t)(o0 + orow) * D_DIM + d0 + tx * 4]) = u;
  }
}

// ---------------- per-(b,e): bitonic sort logits (desc, idx asc), softmax vals for top-K ----------------
// softmax over tokens is monotone in the logit -> top-k by logit == top-k by prob.
__global__ __launch_bounds__(1024) void topk_kernel(const float* __restrict__ logits_t,
                                                    float* __restrict__ vals, int* __restrict__ idxb) {
  __shared__ float sv[S_DIM];
  __shared__ int si[S_DIM];
  __shared__ float red[1024];
  int row = blockIdx.x;  // b*E + e
  int tid = threadIdx.x;
  const float* lp = logits_t + (size_t)row * S_DIM;

  float lmax = -1e30f;
  for (int s = tid; s < S_DIM; s += 1024) {
    float v = lp[s];
    sv[s] = v; si[s] = s;
    lmax = fmaxf(lmax, v);
  }
  red[tid] = lmax; __syncthreads();
  for (int o = 512; o > 0; o >>= 1) {
    if (tid < o) red[tid] = fmaxf(red[tid], red[tid + o]);
    __syncthreads();
  }
  float mx = red[0]; __syncthreads();

  float lsum = 0.f;
  for (int s = tid; s < S_DIM; s += 1024) lsum += expf(sv[s] - mx);
  red[tid] = lsum; __syncthreads();
  for (int o = 512; o > 0; o >>= 1) {
    if (tid < o) red[tid] += red[tid + o];
    __syncthreads();
  }
  float Z = red[0];

  // bitonic sort on (logit desc, idx asc)
  for (int k = 2; k <= S_DIM; k <<= 1) {
    for (int j = k >> 1; j > 0; j >>= 1) {
      __syncthreads();
      for (int i = tid; i < S_DIM; i += 1024) {
        int ixj = i ^ j;
        if (ixj > i) {
          float va = sv[i], vb = sv[ixj];
          int ia = si[i], ib = si[ixj];
          bool a_first = (va > vb) || (va == vb && ia < ib);
          bool up = ((i & k) == 0);
          if (up != a_first) {
            sv[i] = vb; sv[ixj] = va;
            si[i] = ib; si[ixj] = ia;
          }
        }
      }
    }
  }
  __syncthreads();
  for (int t = tid; t < K_SEL; t += 1024) {
    vals[(size_t)row * K_SEL + t] = expf(sv[t] - mx) / Z;
    idxb[(size_t)row * K_SEL + t] = si[t];
  }
}

// ---------------- grouped GEMM, 2-phase double-buffered (T3-minimum recipe) ----------------
// 128x128 tile, BK=64, 4 waves (2x2), mfma_f32_16x16x32_bf16, global_load_lds w16,
// XOR slot-swizzle on GLOBAL SOURCE (linear LDS dest) + on LDS frag reads.
__global__ __launch_bounds__(256) void moe_gemm_kernel(
    const unsigned short* __restrict__ xb,   // [B,S,D] bf16
    const unsigned short* __restrict__ wt,   // [E,O,D] bf16
    const int* __restrict__ idxbuf,          // [B*E,K]
    const float* __restrict__ valbuf,        // [B*E,K]
    const float* __restrict__ bias,          // [E]
    float* __restrict__ out)                 // [B,S,O] fp32
{
  __shared__ __align__(16) unsigned short lA[2][128 * 64];
  __shared__ __align__(16) unsigned short lB[2][128 * 64];

  const int tid = threadIdx.x;
  const int wv = tid >> 6, ln = tid & 63;
  const int grp = blockIdx.z;            // b*E + e
  const int bi = grp >> 4, ei = grp & 15;
  const int m0 = blockIdx.y * 128;
  const int n0 = blockIdx.x * 128;
  const int wm = wv >> 1, wn = wv & 1;

  const unsigned short* aSrc[4];
  const unsigned short* bSrc[4];
#pragma unroll
  for (int t = 0; t < 4; ++t) {
    int row = t * 32 + (tid >> 3);
    int lslot = (tid & 7) ^ (row & 7);
    int tok = idxbuf[grp * K_SEL + m0 + row];
    aSrc[t] = xb + ((size_t)bi * S_DIM + tok) * D_DIM + lslot * 8;
    int oc = n0 + row;
    bSrc[t] = wt + ((size_t)ei * O_DIM + oc) * D_DIM + lslot * 8;
  }

  f32x4 acc[4][4];
  f32x4 zero4 = {0.f, 0.f, 0.f, 0.f};
#pragma unroll
  for (int i = 0; i < 4; ++i)
#pragma unroll
    for (int j = 0; j < 4; ++j) acc[i][j] = zero4;

#define STAGE(buf, kt)                                                                     \
  do {                                                                                     \
    _Pragma("unroll") for (int t = 0; t < 4; ++t) {                                        \
      __builtin_amdgcn_global_load_lds(                                                    \
          (const __attribute__((address_space(1))) void*)(aSrc[t] + (kt) * 64),            \
          (__attribute__((address_space(3))) void*)(&lA[buf][t * 2048 + wv * 512]), 16, 0, 0); \
      __builtin_amdgcn_global_load_lds(                                                    \
          (const __attribute__((address_space(1))) void*)(bSrc[t] + (kt) * 64),            \
          (__attribute__((address_space(3))) void*)(&lB[buf][t * 2048 + wv * 512]), 16, 0, 0); \
    }                                                                                      \
  } while (0)

#define COMPUTE(buf)                                                                       \
  do {                                                                                     \
    _Pragma("unroll") for (int ks = 0; ks < 2; ++ks) {                                     \
      s16x8 af[4], bfr[4];                                                                 \
      _Pragma("unroll") for (int i = 0; i < 4; ++i) {                                      \
        int row = wm * 64 + i * 16 + (ln & 15);                                            \
        int slot = (ks * 4 + (ln >> 4)) ^ (row & 7);                                       \
        af[i] = *(const s16x8*)&lA[buf][row * 64 + slot * 8];                              \
      }                                                                                    \
      _Pragma("unroll") for (int j = 0; j < 4; ++j) {                                      \
        int row = wn * 64 + j * 16 + (ln & 15);                                            \
        int slot = (ks * 4 + (ln >> 4)) ^ (row & 7);                                       \
        bfr[j] = *(const s16x8*)&lB[buf][row * 64 + slot * 8];                             \
      }                                                                                    \
      _Pragma("unroll") for (int i = 0; i < 4; ++i)                                        \
        _Pragma("unroll") for (int j = 0; j < 4; ++j)                                      \
          acc[i][j] = __builtin_amdgcn_mfma_f32_16x16x32_bf16(af[i], bfr[j], acc[i][j], 0, 0, 0); \
    }                                                                                      \
  } while (0)

  // prologue: stage tile 0, drain, then 2-phase loop (loads for t+1 in flight under compute of t)
  STAGE(0, 0);
  __syncthreads();
  int cur = 0;
  for (int kt = 0; kt < D_DIM / 64 - 1; ++kt) {
    STAGE(cur ^ 1, kt + 1);
    COMPUTE(cur);
    __syncthreads();   // drains vmcnt(0): next buffer ready; all reads of cur done
    cur ^= 1;
  }
  COMPUTE(cur);

  const float be = bias[ei];
#pragma unroll
  for (int i = 0; i < 4; ++i) {
#pragma unroll
    for (int r = 0; r < 4; ++r) {
      int krow = m0 + wm * 64 + i * 16 + (ln >> 4) * 4 + r;
      int tok = idxbuf[grp * K_SEL + krow];
      float vv = valbuf[grp * K_SEL + krow];
      float* orow = out + ((size_t)bi * S_DIM + tok) * O_DIM;
#pragma unroll
      for (int j = 0; j < 4; ++j) {
        int col = n0 + wn * 64 + j * 16 + (ln & 15);
        atomicAdd(&orow[col], (acc[i][j][r] + be) / vv);
      }
    }
  }
#undef STAGE
#undef COMPUTE
}

extern "C" void kernel_launch(void* const* d_in, const int* in_sizes, int n_in,
                              void* d_out, int out_size, void* d_ws, size_t ws_size,
                              hipStream_t stream) {
  const float* x   = (const float*)d_in[0];
  const float* gw  = (const float*)d_in[1];
  const float* gb  = (const float*)d_in[2];
  const float* w   = (const float*)d_in[3];
  const float* bia = (const float*)d_in[4];
  float* out = (float*)d_out;

  char* ws = (char*)d_ws;
  float*          logits_t = (float*)ws;                                   // 512 KB
  float*          vals     = (float*)(ws + 524288);                        // 128 KB
  int*            idxb     = (int*)(ws + 655360);                          // 128 KB
  unsigned short* xbf      = (unsigned short*)(ws + 786432);               // 16 MB
  unsigned short* wtb      = (unsigned short*)(ws + 786432 + 16777216);    // 32 MB

  hipMemsetAsync(d_out, 0, (size_t)out_size * sizeof(float), stream);

  transpose_w_kernel<<<dim3(O_DIM / 64, D_DIM / 64, E_NUM), dim3(256), 0, stream>>>(w, wtb);
  gate_kernel<<<dim3((B_NUM * S_DIM) / 4), dim3(256), 0, stream>>>(x, gw, gb, logits_t, xbf);
  topk_kernel<<<dim3(B_NUM * E_NUM), dim3(1024), 0, stream>>>(logits_t, vals, idxb);
  moe_gemm_kernel<<<dim3(O_DIM / 128, K_SEL / 128, B_NUM * E_NUM), dim3(256), 0, stream>>>(
      xbf, wtb, idxb, vals, bia, out);
}

// Round 3
// 276.612 us; speedup vs baseline: 1.1536x; 1.0291x over previous
//
#include <hip/hip_runtime.h>

#define B_NUM 4
#define S_DIM 2048
#define D_DIM 1024
#define O_DIM 1024
#define E_NUM 16
#define K_SEL 512

typedef __attribute__((ext_vector_type(4))) float f32x4;
typedef __attribute__((ext_vector_type(8))) short s16x8;

__device__ __forceinline__ unsigned short f2b(float f) {
  union { float f; unsigned int u; } c; c.f = f;
  unsigned int u = c.u;
  u += 0x7fffu + ((u >> 16) & 1u);   // RNE to bf16
  return (unsigned short)(u >> 16);
}

// ---------------- gate + x-convert fused ----------------
__global__ __launch_bounds__(256) void gate_kernel(const float* __restrict__ x,
                                                   const float* __restrict__ gw,
                                                   const float* __restrict__ gb,
                                                   float* __restrict__ logits_t,
                                                   unsigned short* __restrict__ xb) {
  int wave = (blockIdx.x * blockDim.x + threadIdx.x) >> 6;  // token index
  int ln = threadIdx.x & 63;
  int bi = wave / S_DIM, s = wave % S_DIM;
  const float* xr = x + (size_t)wave * D_DIM;
  unsigned short* xbr = xb + (size_t)wave * D_DIM;
  float acc[E_NUM];
#pragma unroll
  for (int e = 0; e < E_NUM; ++e) acc[e] = 0.f;
#pragma unroll
  for (int it = 0; it < 4; ++it) {
    int d0 = it * 256 + ln * 4;
    float4 xv = *reinterpret_cast<const float4*>(&xr[d0]);
    ushort4 u;
    u.x = f2b(xv.x); u.y = f2b(xv.y); u.z = f2b(xv.z); u.w = f2b(xv.w);
    *reinterpret_cast<ushort4*>(&xbr[d0]) = u;
    const float* g = gw + (size_t)d0 * E_NUM;
#pragma unroll
    for (int e = 0; e < E_NUM; ++e)
      acc[e] = fmaf(xv.x, g[e], fmaf(xv.y, g[E_NUM + e],
               fmaf(xv.z, g[2 * E_NUM + e], fmaf(xv.w, g[3 * E_NUM + e], acc[e]))));
  }
  float myv = 0.f;
#pragma unroll
  for (int e = 0; e < E_NUM; ++e) {
    float v = acc[e];
#pragma unroll
    for (int o = 32; o > 0; o >>= 1) v += __shfl_xor(v, o);
    if (ln == e) myv = v;
  }
  if (ln < E_NUM)
    logits_t[((size_t)bi * E_NUM + ln) * S_DIM + s] = myv + gb[ln];
}

// ---------------- w[e][d][o] fp32 -> wT[e][o][d] bf16, 64x64 tiles ----------------
__global__ __launch_bounds__(256) void transpose_w_kernel(const float* __restrict__ w,
                                                          unsigned short* __restrict__ wt) {
  __shared__ float tile[64][65];
  int e = blockIdx.z;
  int d0 = blockIdx.y * 64, o0 = blockIdx.x * 64;
  int tx = threadIdx.x & 15, ty = threadIdx.x >> 4;
  const float* wbase = w + (size_t)e * D_DIM * O_DIM;
#pragma unroll
  for (int r = 0; r < 4; ++r) {
    int row = r * 16 + ty;
    float4 v = *reinterpret_cast<const float4*>(&wbase[(size_t)(d0 + row) * O_DIM + o0 + tx * 4]);
    tile[row][tx * 4 + 0] = v.x; tile[row][tx * 4 + 1] = v.y;
    tile[row][tx * 4 + 2] = v.z; tile[row][tx * 4 + 3] = v.w;
  }
  __syncthreads();
  unsigned short* wtb = wt + (size_t)e * O_DIM * D_DIM;
#pragma unroll
  for (int r = 0; r < 4; ++r) {
    int orow = r * 16 + ty;
    ushort4 u;
    u.x = f2b(tile[tx * 4 + 0][orow]);
    u.y = f2b(tile[tx * 4 + 1][orow]);
    u.z = f2b(tile[tx * 4 + 2][orow]);
    u.w = f2b(tile[tx * 4 + 3][orow]);
    *reinterpret_cast<ushort4*>(&wtb[(size_t)(o0 + orow) * D_DIM + d0 + tx * 4]) = u;
  }
}

// ---------------- per-(b,e): bitonic sort logits (desc, idx asc), softmax vals for top-K ----------------
__global__ __launch_bounds__(1024) void topk_kernel(const float* __restrict__ logits_t,
                                                    float* __restrict__ vals, int* __restrict__ idxb) {
  __shared__ float sv[S_DIM];
  __shared__ int si[S_DIM];
  __shared__ float red[1024];
  int row = blockIdx.x;
  int tid = threadIdx.x;
  const float* lp = logits_t + (size_t)row * S_DIM;

  float lmax = -1e30f;
  for (int s = tid; s < S_DIM; s += 1024) {
    float v = lp[s];
    sv[s] = v; si[s] = s;
    lmax = fmaxf(lmax, v);
  }
  red[tid] = lmax; __syncthreads();
  for (int o = 512; o > 0; o >>= 1) {
    if (tid < o) red[tid] = fmaxf(red[tid], red[tid + o]);
    __syncthreads();
  }
  float mx = red[0]; __syncthreads();

  float lsum = 0.f;
  for (int s = tid; s < S_DIM; s += 1024) lsum += expf(sv[s] - mx);
  red[tid] = lsum; __syncthreads();
  for (int o = 512; o > 0; o >>= 1) {
    if (tid < o) red[tid] += red[tid + o];
    __syncthreads();
  }
  float Z = red[0];

  for (int k = 2; k <= S_DIM; k <<= 1) {
    for (int j = k >> 1; j > 0; j >>= 1) {
      __syncthreads();
      for (int i = tid; i < S_DIM; i += 1024) {
        int ixj = i ^ j;
        if (ixj > i) {
          float va = sv[i], vb = sv[ixj];
          int ia = si[i], ib = si[ixj];
          bool a_first = (va > vb) || (va == vb && ia < ib);
          bool up = ((i & k) == 0);
          if (up != a_first) {
            sv[i] = vb; sv[ixj] = va;
            si[i] = ib; si[ixj] = ia;
          }
        }
      }
    }
  }
  __syncthreads();
  for (int t = tid; t < K_SEL; t += 1024) {
    vals[(size_t)row * K_SEL + t] = expf(sv[t] - mx) / Z;
    idxb[(size_t)row * K_SEL + t] = si[t];
  }
}

// ---------------- grouped GEMM: 256x256 tile, BK=64, 8 waves, 8-phase-style schedule ----------------
// Raw s_barrier (no vmcnt drain), counted vmcnt(4)/vmcnt(2), per-phase {ds_read || stage || MFMA}.
__global__ __launch_bounds__(512, 1) void moe_gemm_kernel(
    const unsigned short* __restrict__ xb,   // [B,S,D] bf16
    const unsigned short* __restrict__ wt,   // [E,O,D] bf16
    const int* __restrict__ idxbuf,          // [B*E,K]
    const float* __restrict__ valbuf,        // [B*E,K]
    const float* __restrict__ bias,          // [E]
    float* __restrict__ out)                 // [B,S,O] fp32
{
  __shared__ __align__(16) unsigned short lA[2][256 * 64];
  __shared__ __align__(16) unsigned short lB[2][256 * 64];

  const int tid = threadIdx.x;
  const int wv = tid >> 6, ln = tid & 63;
  const int wm = wv >> 2, wn = wv & 3;     // 2M x 4N wave grid; wave tile 128x64

  const int bid = blockIdx.x;
  const int swz = (bid & 7) * 64 + (bid >> 3);   // XCD-chunked (512 % 8 == 0, bijective)
  const int n0 = (swz & 3) * 256;
  const int m0 = ((swz >> 2) & 1) * 256;
  const int grp = swz >> 3;                // b*E + e
  const int bi = grp >> 4, ei = grp & 15;

  // staging sources: per thread, 4 rows of A (gathered tokens) and 4 rows of B.
  // wave wv covers rows s*64 + wv*8 + (ln>>3); slot swizzle on the GLOBAL source.
  const unsigned short* aSrcP[4];
  const unsigned short* bSrcP[4];
  const int lslot = (ln & 7) ^ (ln >> 3);
#pragma unroll
  for (int s = 0; s < 4; ++s) {
    const int r = s * 64 + wv * 8 + (ln >> 3);
    const int tok = idxbuf[grp * K_SEL + m0 + r];
    aSrcP[s] = xb + ((size_t)bi * S_DIM + tok) * D_DIM + lslot * 8;
    bSrcP[s] = wt + ((size_t)ei * O_DIM + (n0 + r)) * D_DIM + lslot * 8;
  }

  const unsigned rowA = wm * 128 + (ln & 15);
  const unsigned rowB = wn * 64 + (ln & 15);
  const unsigned phys0 = (ln >> 4) ^ (ln & 7);        // swizzled slot, kslice 0
  const unsigned phys1 = (4 + (ln >> 4)) ^ (ln & 7);  // swizzled slot, kslice 1

  f32x4 acc[8][4];
  f32x4 zero4 = {0.f, 0.f, 0.f, 0.f};
#pragma unroll
  for (int i = 0; i < 8; ++i)
#pragma unroll
    for (int j = 0; j < 4; ++j) acc[i][j] = zero4;

  s16x8 bfr[4][2];

#define GLD(dst, src)                                                          \
  __builtin_amdgcn_global_load_lds(                                            \
      (const __attribute__((address_space(1))) void*)(src),                    \
      (__attribute__((address_space(3))) void*)(dst), 16, 0, 0)
#define VMW(N) asm volatile("s_waitcnt vmcnt(" #N ")" ::: "memory")
#define LGKM0 asm volatile("s_waitcnt lgkmcnt(0)" ::: "memory")
#define DS_A(CUR, i, PH) (*(const s16x8*)&lA[CUR][rowA * 64u + (i) * 1024u + (PH) * 8u])
#define DS_B(CUR, j, PH) (*(const s16x8*)&lB[CUR][rowB * 64u + (j) * 1024u + (PH) * 8u])

#define MFMA16(P)                                                              \
  __builtin_amdgcn_s_setprio(1);                                               \
  _Pragma("unroll") for (int jj = 0; jj < 4; ++jj) {                           \
    acc[2*(P)][jj]   = __builtin_amdgcn_mfma_f32_16x16x32_bf16(aL0, bfr[jj][0], acc[2*(P)][jj], 0, 0, 0);   \
    acc[2*(P)][jj]   = __builtin_amdgcn_mfma_f32_16x16x32_bf16(aL1, bfr[jj][1], acc[2*(P)][jj], 0, 0, 0);   \
    acc[2*(P)+1][jj] = __builtin_amdgcn_mfma_f32_16x16x32_bf16(aH0, bfr[jj][0], acc[2*(P)+1][jj], 0, 0, 0); \
    acc[2*(P)+1][jj] = __builtin_amdgcn_mfma_f32_16x16x32_bf16(aH1, bfr[jj][1], acc[2*(P)+1][jj], 0, 0, 0); \
  }                                                                            \
  __builtin_amdgcn_s_setprio(0);

// One K-tile = 4 phases. Phase p computes M-frags {2p,2p+1} x all 4 N-frags x 2 kslices.
// Staging order (next tile): B rows0-127 | B rows128-255 | A q0,q2 | A q1,q3 — matches read order.
#define KTILE(CUR, NXT, KT, DOSTAGE, VM1, VM3)                                 \
  {                                                                            \
    { /* phase 0 */                                                            \
      _Pragma("unroll") for (int jj = 0; jj < 4; ++jj) {                       \
        bfr[jj][0] = DS_B(CUR, jj, phys0);                                     \
        bfr[jj][1] = DS_B(CUR, jj, phys1);                                     \
      }                                                                        \
      s16x8 aL0 = DS_A(CUR, 0, phys0), aL1 = DS_A(CUR, 0, phys1);              \
      s16x8 aH0 = DS_A(CUR, 1, phys0), aH1 = DS_A(CUR, 1, phys1);              \
      if (DOSTAGE) {                                                           \
        GLD(&lB[NXT][(wv * 8) * 64],        bSrcP[0] + (KT) * 64);             \
        GLD(&lB[NXT][(64 + wv * 8) * 64],   bSrcP[1] + (KT) * 64);             \
      }                                                                        \
      __builtin_amdgcn_s_barrier();                                            \
      LGKM0; __builtin_amdgcn_sched_barrier(0);                                \
      MFMA16(0);                                                               \
      __builtin_amdgcn_s_barrier();                                            \
    }                                                                          \
    { /* phase 1 */                                                            \
      s16x8 aL0 = DS_A(CUR, 2, phys0), aL1 = DS_A(CUR, 2, phys1);              \
      s16x8 aH0 = DS_A(CUR, 3, phys0), aH1 = DS_A(CUR, 3, phys1);              \
      if (DOSTAGE) {                                                           \
        GLD(&lB[NXT][(128 + wv * 8) * 64],  bSrcP[2] + (KT) * 64);             \
        GLD(&lB[NXT][(192 + wv * 8) * 64],  bSrcP[3] + (KT) * 64);             \
      }                                                                        \
      VM1;                                                                     \
      __builtin_amdgcn_s_barrier();                                            \
      LGKM0; __builtin_amdgcn_sched_barrier(0);                                \
      MFMA16(1);                                                               \
      __builtin_amdgcn_s_barrier();                                            \
    }                                                                          \
    { /* phase 2 */                                                            \
      s16x8 aL0 = DS_A(CUR, 4, phys0), aL1 = DS_A(CUR, 4, phys1);              \
      s16x8 aH0 = DS_A(CUR, 5, phys0), aH1 = DS_A(CUR, 5, phys1);              \
      if (DOSTAGE) {                                                           \
        GLD(&lA[NXT][(wv * 8) * 64],        aSrcP[0] + (KT) * 64);             \
        GLD(&lA[NXT][(128 + wv * 8) * 64],  aSrcP[2] + (KT) * 64);             \
      }                                                                        \
      __builtin_amdgcn_s_barrier();                                            \
      LGKM0; __builtin_amdgcn_sched_barrier(0);                                \
      MFMA16(2);                                                               \
      __builtin_amdgcn_s_barrier();                                            \
    }                                                                          \
    { /* phase 3 */                                                            \
      s16x8 aL0 = DS_A(CUR, 6, phys0), aL1 = DS_A(CUR, 6, phys1);              \
      s16x8 aH0 = DS_A(CUR, 7, phys0), aH1 = DS_A(CUR, 7, phys1);              \
      if (DOSTAGE) {                                                           \
        GLD(&lA[NXT][(64 + wv * 8) * 64],   aSrcP[1] + (KT) * 64);             \
        GLD(&lA[NXT][(192 + wv * 8) * 64],  aSrcP[3] + (KT) * 64);             \
      }                                                                        \
      VM3;                                                                     \
      __builtin_amdgcn_s_barrier();                                            \
      LGKM0; __builtin_amdgcn_sched_barrier(0);                                \
      MFMA16(3);                                                               \
      __builtin_amdgcn_s_barrier();                                            \
    }                                                                          \
  }

  // prologue: stage tile 0 into buf0, full drain once.
  GLD(&lB[0][(wv * 8) * 64],        bSrcP[0]);
  GLD(&lB[0][(64 + wv * 8) * 64],   bSrcP[1]);
  GLD(&lB[0][(128 + wv * 8) * 64],  bSrcP[2]);
  GLD(&lB[0][(192 + wv * 8) * 64],  bSrcP[3]);
  GLD(&lA[0][(wv * 8) * 64],        aSrcP[0]);
  GLD(&lA[0][(128 + wv * 8) * 64],  aSrcP[2]);
  GLD(&lA[0][(64 + wv * 8) * 64],   aSrcP[1]);
  GLD(&lA[0][(192 + wv * 8) * 64],  aSrcP[3]);
  VMW(0);
  __builtin_amdgcn_s_barrier();

  // 16 K-tiles total (D=1024, BK=64). Ping-pong with compile-time buffer ids.
  for (int t = 0; t < 14; t += 2) {
    KTILE(0, 1, t + 1, 1, VMW(4), VMW(2));
    KTILE(1, 0, t + 2, 1, VMW(4), VMW(2));
  }
  KTILE(0, 1, 15, 1, VMW(4), VMW(2));       // compute tile 14, stage tile 15
  KTILE(1, 0, 0, 0, VMW(0), ((void)0));     // compute tile 15, no staging

  // epilogue: (acc + b[e]) / val, atomic scatter-add
  const float be = bias[ei];
#pragma unroll
  for (int i = 0; i < 8; ++i) {
#pragma unroll
    for (int r = 0; r < 4; ++r) {
      int krow = m0 + wm * 128 + i * 16 + (ln >> 4) * 4 + r;
      int tok = idxbuf[grp * K_SEL + krow];
      float vv = valbuf[grp * K_SEL + krow];
      float* orow = out + ((size_t)bi * S_DIM + tok) * O_DIM;
#pragma unroll
      for (int j = 0; j < 4; ++j) {
        int col = n0 + wn * 64 + j * 16 + (ln & 15);
        atomicAdd(&orow[col], (acc[i][j][r] + be) / vv);
      }
    }
  }
#undef GLD
#undef VMW
#undef LGKM0
#undef DS_A
#undef DS_B
#undef MFMA16
#undef KTILE
}

extern "C" void kernel_launch(void* const* d_in, const int* in_sizes, int n_in,
                              void* d_out, int out_size, void* d_ws, size_t ws_size,
                              hipStream_t stream) {
  const float* x   = (const float*)d_in[0];
  const float* gw  = (const float*)d_in[1];
  const float* gb  = (const float*)d_in[2];
  const float* w   = (const float*)d_in[3];
  const float* bia = (const float*)d_in[4];
  float* out = (float*)d_out;

  char* ws = (char*)d_ws;
  float*          logits_t = (float*)ws;                                   // 512 KB
  float*          vals     = (float*)(ws + 524288);                        // 128 KB
  int*            idxb     = (int*)(ws + 655360);                          // 128 KB
  unsigned short* xbf      = (unsigned short*)(ws + 786432);               // 16 MB
  unsigned short* wtb      = (unsigned short*)(ws + 786432 + 16777216);    // 32 MB

  hipMemsetAsync(d_out, 0, (size_t)out_size * sizeof(float), stream);

  transpose_w_kernel<<<dim3(O_DIM / 64, D_DIM / 64, E_NUM), dim3(256), 0, stream>>>(w, wtb);
  gate_kernel<<<dim3((B_NUM * S_DIM) / 4), dim3(256), 0, stream>>>(x, gw, gb, logits_t, xbf);
  topk_kernel<<<dim3(B_NUM * E_NUM), dim3(1024), 0, stream>>>(logits_t, vals, idxb);
  moe_gemm_kernel<<<dim3(512), dim3(512), 0, stream>>>(xbf, wtb, idxb, vals, bia, out);
}

// Round 4
// 216.451 us; speedup vs baseline: 1.4743x; 1.2779x over previous
//
#include <hip/hip_runtime.h>

#define B_NUM 4
#define S_DIM 2048
#define D_DIM 1024
#define O_DIM 1024
#define E_NUM 16
#define K_SEL 512

typedef __attribute__((ext_vector_type(4))) float f32x4;
typedef __attribute__((ext_vector_type(8))) short s16x8;

__device__ __forceinline__ unsigned short f2b(float f) {
  union { float f; unsigned int u; } c; c.f = f;
  unsigned int u = c.u;
  u += 0x7fffu + ((u >> 16) & 1u);   // RNE to bf16
  return (unsigned short)(u >> 16);
}
__device__ __forceinline__ float b2f(unsigned short h) {
  union { unsigned int u; float f; } c; c.u = (unsigned int)h << 16; return c.f;
}

// ---------------- fused prep: blocks [0,4096) transpose w; [4096,6144) gate+convert ----------------
__global__ __launch_bounds__(256) void prep_kernel(const float* __restrict__ w,
                                                   unsigned short* __restrict__ wt,
                                                   const float* __restrict__ x,
                                                   const float* __restrict__ gw,
                                                   const float* __restrict__ gb,
                                                   float* __restrict__ logits_t,
                                                   unsigned short* __restrict__ xb) {
  if (blockIdx.x < 4096) {
    // ---- transpose w[e][d][o] -> wt[e][o][d] bf16, 64x64 tile ----
    __shared__ float tile[64][65];
    int bx = blockIdx.x;
    int e = bx >> 8, d0 = ((bx >> 4) & 15) * 64, o0 = (bx & 15) * 64;
    int tx = threadIdx.x & 15, ty = threadIdx.x >> 4;
    const float* wbase = w + (size_t)e * D_DIM * O_DIM;
#pragma unroll
    for (int r = 0; r < 4; ++r) {
      int row = r * 16 + ty;
      float4 v = *reinterpret_cast<const float4*>(&wbase[(size_t)(d0 + row) * O_DIM + o0 + tx * 4]);
      tile[row][tx * 4 + 0] = v.x; tile[row][tx * 4 + 1] = v.y;
      tile[row][tx * 4 + 2] = v.z; tile[row][tx * 4 + 3] = v.w;
    }
    __syncthreads();
    unsigned short* wtb = wt + (size_t)e * O_DIM * D_DIM;
#pragma unroll
    for (int r = 0; r < 4; ++r) {
      int orow = r * 16 + ty;
      ushort4 u;
      u.x = f2b(tile[tx * 4 + 0][orow]);
      u.y = f2b(tile[tx * 4 + 1][orow]);
      u.z = f2b(tile[tx * 4 + 2][orow]);
      u.w = f2b(tile[tx * 4 + 3][orow]);
      *reinterpret_cast<ushort4*>(&wtb[(size_t)(o0 + orow) * D_DIM + d0 + tx * 4]) = u;
    }
  } else {
    // ---- gate logits (fp32) + x -> bf16 ----
    int wave = ((blockIdx.x - 4096) * 256 + threadIdx.x) >> 6;  // token index
    int ln = threadIdx.x & 63;
    int bi = wave / S_DIM, s = wave % S_DIM;
    const float* xr = x + (size_t)wave * D_DIM;
    unsigned short* xbr = xb + (size_t)wave * D_DIM;
    float acc[E_NUM];
#pragma unroll
    for (int e = 0; e < E_NUM; ++e) acc[e] = 0.f;
#pragma unroll
    for (int it = 0; it < 4; ++it) {
      int d0 = it * 256 + ln * 4;
      float4 xv = *reinterpret_cast<const float4*>(&xr[d0]);
      ushort4 u;
      u.x = f2b(xv.x); u.y = f2b(xv.y); u.z = f2b(xv.z); u.w = f2b(xv.w);
      *reinterpret_cast<ushort4*>(&xbr[d0]) = u;
      const float* g = gw + (size_t)d0 * E_NUM;
#pragma unroll
      for (int e = 0; e < E_NUM; ++e)
        acc[e] = fmaf(xv.x, g[e], fmaf(xv.y, g[E_NUM + e],
                 fmaf(xv.z, g[2 * E_NUM + e], fmaf(xv.w, g[3 * E_NUM + e], acc[e]))));
    }
    float myv = 0.f;
#pragma unroll
    for (int e = 0; e < E_NUM; ++e) {
      float v = acc[e];
#pragma unroll
      for (int o = 32; o > 0; o >>= 1) v += __shfl_xor(v, o);
      if (ln == e) myv = v;
    }
    if (ln < E_NUM)
      logits_t[((size_t)bi * E_NUM + ln) * S_DIM + s] = myv + gb[ln];
  }
}

// ---------------- per-(b,e): softmax consts + radix-select top-512 + inverted index ----------------
// Selection = exact top-K by (logit desc, idx asc); output order within the K slots is arbitrary
// (scatter-add is assignment-invariant as long as idx/val/k-slot pairing is consistent).
__global__ __launch_bounds__(256) void topk_kernel(const float* __restrict__ logits_t,
                                                   float* __restrict__ vals, int* __restrict__ idxb,
                                                   int* __restrict__ cnt, int* __restrict__ hslot) {
  __shared__ float red[256];
  __shared__ int hist[256];
  __shared__ unsigned sh_prefix;
  __shared__ int sh_need;
  __shared__ int outc;
  __shared__ unsigned tiebm[64];
  __shared__ int wordpfx[64];

  const int row = blockIdx.x;           // b*E + e
  const int bi = row >> 4, ei = row & 15;
  const int tid = threadIdx.x;
  const float* lp = logits_t + (size_t)row * S_DIM;

  float v[8];
  unsigned key[8];
  float lmax = -1e30f;
#pragma unroll
  for (int j = 0; j < 8; ++j) {
    float f = lp[j * 256 + tid];
    v[j] = f;
    unsigned u = __float_as_uint(f);
    key[j] = (u & 0x80000000u) ? ~u : (u | 0x80000000u);  // ascending uint == ascending float
    lmax = fmaxf(lmax, f);
  }
  red[tid] = lmax; __syncthreads();
  for (int o = 128; o > 0; o >>= 1) {
    if (tid < o) red[tid] = fmaxf(red[tid], red[tid + o]);
    __syncthreads();
  }
  const float mx = red[0]; __syncthreads();
  float lsum = 0.f;
#pragma unroll
  for (int j = 0; j < 8; ++j) lsum += expf(v[j] - mx);
  red[tid] = lsum; __syncthreads();
  for (int o = 128; o > 0; o >>= 1) {
    if (tid < o) red[tid] += red[tid + o];
    __syncthreads();
  }
  const float Z = red[0];

  // --- radix select (MSB-first, 4x8 bits): find threshold key T, take all >T plus need_rem ==T ---
  unsigned prefix = 0;
  int need = K_SEL;
#pragma unroll
  for (int pass = 0; pass < 4; ++pass) {
    const int shift = 24 - pass * 8;
    __syncthreads();
    hist[tid] = 0;
    __syncthreads();
    const unsigned pmask = (pass == 0) ? 0u : (0xFFFFFFFFu << (shift + 8));
#pragma unroll
    for (int j = 0; j < 8; ++j)
      if ((key[j] & pmask) == prefix) atomicAdd(&hist[(key[j] >> shift) & 0xFF], 1);
    __syncthreads();
    if (tid == 0) {
      int cum = 0, bsel = 0;
      for (int b = 255; b >= 0; --b) {
        cum += hist[b];
        if (cum >= need) { bsel = b; break; }
      }
      sh_prefix = prefix | ((unsigned)bsel << shift);
      sh_need = need - (cum - hist[bsel]);  // still needed from the == bucket
    }
    __syncthreads();
    prefix = sh_prefix;
    need = sh_need;
  }
  const unsigned T = prefix;
  const int need_rem = need;

  if (tid == 0) outc = 0;
  if (tid < 64) tiebm[tid] = 0;
  __syncthreads();

#pragma unroll
  for (int j = 0; j < 8; ++j) {
    const int s = j * 256 + tid;
    if (key[j] > T) {
      int p = atomicAdd(&outc, 1);
      vals[row * K_SEL + p] = expf(v[j] - mx) / Z;
      idxb[row * K_SEL + p] = s;
      int hp = atomicAdd(&cnt[bi * S_DIM + s], 1);
      hslot[(bi * S_DIM + s) * 16 + hp] = ei * K_SEL + p;
    } else if (key[j] == T) {
      atomicOr(&tiebm[s >> 5], 1u << (s & 31));
    }
  }
  __syncthreads();
  if (tid == 0) {
    int c = 0;
    for (int w2 = 0; w2 < 64; ++w2) { wordpfx[w2] = c; c += __popc(tiebm[w2]); }
  }
  __syncthreads();
  if (tid < 64) {
    unsigned m = tiebm[tid];
    int base = wordpfx[tid];
    const int p0 = outc;  // all >T entries placed in [0, outc)
    while (m) {
      int bit = __ffs(m) - 1;
      m &= m - 1;
      if (base < need_rem) {
        int s = tid * 32 + bit;
        int p = p0 + base;
        vals[row * K_SEL + p] = expf(lp[s] - mx) / Z;
        idxb[row * K_SEL + p] = s;
        int hp = atomicAdd(&cnt[bi * S_DIM + s], 1);
        hslot[(bi * S_DIM + s) * 16 + hp] = ei * K_SEL + p;
      }
      base++;
    }
  }
}

// ---------------- grouped GEMM: 256x256, BK=64, 8 waves, phased schedule, counted vmcnt ----------------
// Epilogue: plain bf16 stores of (acc+b)/val into dense tmp[grp][k][O] (no atomics).
__global__ __launch_bounds__(512, 1) void moe_gemm_kernel(
    const unsigned short* __restrict__ xb,   // [B,S,D] bf16
    const unsigned short* __restrict__ wt,   // [E,O,D] bf16
    const int* __restrict__ idxbuf,          // [B*E,K]
    const float* __restrict__ valbuf,        // [B*E,K]
    const float* __restrict__ bias,          // [E]
    unsigned short* __restrict__ tmp)        // [B*E,K,O] bf16
{
  __shared__ __align__(16) unsigned short lA[2][256 * 64];
  __shared__ __align__(16) unsigned short lB[2][256 * 64];

  const int tid = threadIdx.x;
  const int wv = tid >> 6, ln = tid & 63;
  const int wm = wv >> 2, wn = wv & 3;     // 2M x 4N wave grid; wave tile 128x64

  const int bid = blockIdx.x;
  const int swz = (bid & 7) * 64 + (bid >> 3);   // XCD-chunked (512 % 8 == 0, bijective)
  const int n0 = (swz & 3) * 256;
  const int m0 = ((swz >> 2) & 1) * 256;
  const int grp = swz >> 3;                // b*E + e
  const int bi = grp >> 4, ei = grp & 15;

  const unsigned short* aSrcP[4];
  const unsigned short* bSrcP[4];
  const int lslot = (ln & 7) ^ (ln >> 3);
#pragma unroll
  for (int s = 0; s < 4; ++s) {
    const int r = s * 64 + wv * 8 + (ln >> 3);
    const int tok = idxbuf[grp * K_SEL + m0 + r];
    aSrcP[s] = xb + ((size_t)bi * S_DIM + tok) * D_DIM + lslot * 8;
    bSrcP[s] = wt + ((size_t)ei * O_DIM + (n0 + r)) * D_DIM + lslot * 8;
  }

  const unsigned rowA = wm * 128 + (ln & 15);
  const unsigned rowB = wn * 64 + (ln & 15);
  const unsigned phys0 = (ln >> 4) ^ (ln & 7);
  const unsigned phys1 = (4 + (ln >> 4)) ^ (ln & 7);

  f32x4 acc[8][4];
  f32x4 zero4 = {0.f, 0.f, 0.f, 0.f};
#pragma unroll
  for (int i = 0; i < 8; ++i)
#pragma unroll
    for (int j = 0; j < 4; ++j) acc[i][j] = zero4;

  s16x8 bfr[4][2];

#define GLD(dst, src)                                                          \
  __builtin_amdgcn_global_load_lds(                                            \
      (const __attribute__((address_space(1))) void*)(src),                    \
      (__attribute__((address_space(3))) void*)(dst), 16, 0, 0)
#define VMW(N) asm volatile("s_waitcnt vmcnt(" #N ")" ::: "memory")
#define LGKM0 asm volatile("s_waitcnt lgkmcnt(0)" ::: "memory")
#define DS_A(CUR, i, PH) (*(const s16x8*)&lA[CUR][rowA * 64u + (i) * 1024u + (PH) * 8u])
#define DS_B(CUR, j, PH) (*(const s16x8*)&lB[CUR][rowB * 64u + (j) * 1024u + (PH) * 8u])

#define MFMA16(P)                                                              \
  __builtin_amdgcn_s_setprio(1);                                               \
  _Pragma("unroll") for (int jj = 0; jj < 4; ++jj) {                           \
    acc[2*(P)][jj]   = __builtin_amdgcn_mfma_f32_16x16x32_bf16(aL0, bfr[jj][0], acc[2*(P)][jj], 0, 0, 0);   \
    acc[2*(P)][jj]   = __builtin_amdgcn_mfma_f32_16x16x32_bf16(aL1, bfr[jj][1], acc[2*(P)][jj], 0, 0, 0);   \
    acc[2*(P)+1][jj] = __builtin_amdgcn_mfma_f32_16x16x32_bf16(aH0, bfr[jj][0], acc[2*(P)+1][jj], 0, 0, 0); \
    acc[2*(P)+1][jj] = __builtin_amdgcn_mfma_f32_16x16x32_bf16(aH1, bfr[jj][1], acc[2*(P)+1][jj], 0, 0, 0); \
  }                                                                            \
  __builtin_amdgcn_s_setprio(0);

#define KTILE(CUR, NXT, KT, DOSTAGE, VM1, VM3)                                 \
  {                                                                            \
    { /* phase 0 */                                                            \
      _Pragma("unroll") for (int jj = 0; jj < 4; ++jj) {                       \
        bfr[jj][0] = DS_B(CUR, jj, phys0);                                     \
        bfr[jj][1] = DS_B(CUR, jj, phys1);                                     \
      }                                                                        \
      s16x8 aL0 = DS_A(CUR, 0, phys0), aL1 = DS_A(CUR, 0, phys1);              \
      s16x8 aH0 = DS_A(CUR, 1, phys0), aH1 = DS_A(CUR, 1, phys1);              \
      if (DOSTAGE) {                                                           \
        GLD(&lB[NXT][(wv * 8) * 64],        bSrcP[0] + (KT) * 64);             \
        GLD(&lB[NXT][(64 + wv * 8) * 64],   bSrcP[1] + (KT) * 64);             \
      }                                                                        \
      __builtin_amdgcn_s_barrier();                                            \
      LGKM0; __builtin_amdgcn_sched_barrier(0);                                \
      MFMA16(0);                                                               \
      __builtin_amdgcn_s_barrier();                                            \
    }                                                                          \
    { /* phase 1 */                                                            \
      s16x8 aL0 = DS_A(CUR, 2, phys0), aL1 = DS_A(CUR, 2, phys1);              \
      s16x8 aH0 = DS_A(CUR, 3, phys0), aH1 = DS_A(CUR, 3, phys1);              \
      if (DOSTAGE) {                                                           \
        GLD(&lB[NXT][(128 + wv * 8) * 64],  bSrcP[2] + (KT) * 64);             \
        GLD(&lB[NXT][(192 + wv * 8) * 64],  bSrcP[3] + (KT) * 64);             \
      }                                                                        \
      VM1;                                                                     \
      __builtin_amdgcn_s_barrier();                                            \
      LGKM0; __builtin_amdgcn_sched_barrier(0);                                \
      MFMA16(1);                                                               \
      __builtin_amdgcn_s_barrier();                                            \
    }                                                                          \
    { /* phase 2 */                                                            \
      s16x8 aL0 = DS_A(CUR, 4, phys0), aL1 = DS_A(CUR, 4, phys1);              \
      s16x8 aH0 = DS_A(CUR, 5, phys0), aH1 = DS_A(CUR, 5, phys1);              \
      if (DOSTAGE) {                                                           \
        GLD(&lA[NXT][(wv * 8) * 64],        aSrcP[0] + (KT) * 64);             \
        GLD(&lA[NXT][(128 + wv * 8) * 64],  aSrcP[2] + (KT) * 64);             \
      }                                                                        \
      __builtin_amdgcn_s_barrier();                                            \
      LGKM0; __builtin_amdgcn_sched_barrier(0);                                \
      MFMA16(2);                                                               \
      __builtin_amdgcn_s_barrier();                                            \
    }                                                                          \
    { /* phase 3 */                                                            \
      s16x8 aL0 = DS_A(CUR, 6, phys0), aL1 = DS_A(CUR, 6, phys1);              \
      s16x8 aH0 = DS_A(CUR, 7, phys0), aH1 = DS_A(CUR, 7, phys1);              \
      if (DOSTAGE) {                                                           \
        GLD(&lA[NXT][(64 + wv * 8) * 64],   aSrcP[1] + (KT) * 64);             \
        GLD(&lA[NXT][(192 + wv * 8) * 64],  aSrcP[3] + (KT) * 64);             \
      }                                                                        \
      VM3;                                                                     \
      __builtin_amdgcn_s_barrier();                                            \
      LGKM0; __builtin_amdgcn_sched_barrier(0);                                \
      MFMA16(3);                                                               \
      __builtin_amdgcn_s_barrier();                                            \
    }                                                                          \
  }

  GLD(&lB[0][(wv * 8) * 64],        bSrcP[0]);
  GLD(&lB[0][(64 + wv * 8) * 64],   bSrcP[1]);
  GLD(&lB[0][(128 + wv * 8) * 64],  bSrcP[2]);
  GLD(&lB[0][(192 + wv * 8) * 64],  bSrcP[3]);
  GLD(&lA[0][(wv * 8) * 64],        aSrcP[0]);
  GLD(&lA[0][(128 + wv * 8) * 64],  aSrcP[2]);
  GLD(&lA[0][(64 + wv * 8) * 64],   aSrcP[1]);
  GLD(&lA[0][(192 + wv * 8) * 64],  aSrcP[3]);
  VMW(0);
  __builtin_amdgcn_s_barrier();

  for (int t = 0; t < 14; t += 2) {
    KTILE(0, 1, t + 1, 1, VMW(4), VMW(2));
    KTILE(1, 0, t + 2, 1, VMW(4), VMW(2));
  }
  KTILE(0, 1, 15, 1, VMW(4), VMW(2));
  KTILE(1, 0, 0, 0, VMW(0), ((void)0));

  // epilogue: (acc + b[e]) / val -> bf16 tmp[grp][krow][col], plain stores
  const float be = bias[ei];
#pragma unroll
  for (int i = 0; i < 8; ++i) {
#pragma unroll
    for (int r = 0; r < 4; ++r) {
      const int krow = m0 + wm * 128 + i * 16 + (ln >> 4) * 4 + r;
      const float inv = 1.0f / valbuf[grp * K_SEL + krow];
      unsigned short* trow = tmp + ((size_t)grp * K_SEL + krow) * O_DIM;
#pragma unroll
      for (int j = 0; j < 4; ++j) {
        const int col = n0 + wn * 64 + j * 16 + (ln & 15);
        trow[col] = f2b((acc[i][j][r] + be) * inv);
      }
    }
  }
#undef GLD
#undef VMW
#undef LGKM0
#undef DS_A
#undef DS_B
#undef MFMA16
#undef KTILE
}

// ---------------- per-token gather-reduce: out[b,s,:] = sum over selecting experts ----------------
__global__ __launch_bounds__(256) void reduce_kernel(const unsigned short* __restrict__ tmp,
                                                     const int* __restrict__ cnt,
                                                     const int* __restrict__ hslot,
                                                     float* __restrict__ out) {
  const int t = blockIdx.x;        // b*S + s
  const int bi = t >> 11;
  const int tid = threadIdx.x;
  const int n = cnt[t];
  float4 a = {0.f, 0.f, 0.f, 0.f};
  for (int h = 0; h < n; ++h) {
    const int u = hslot[t * 16 + h];  // e*K + p
    const unsigned short* tr = tmp + ((size_t)bi * E_NUM * K_SEL + u) * O_DIM + tid * 4;
    ushort4 q = *reinterpret_cast<const ushort4*>(tr);
    a.x += b2f(q.x); a.y += b2f(q.y); a.z += b2f(q.z); a.w += b2f(q.w);
  }
  *reinterpret_cast<float4*>(&out[(size_t)t * O_DIM + tid * 4]) = a;
}

extern "C" void kernel_launch(void* const* d_in, const int* in_sizes, int n_in,
                              void* d_out, int out_size, void* d_ws, size_t ws_size,
                              hipStream_t stream) {
  const float* x   = (const float*)d_in[0];
  const float* gw  = (const float*)d_in[1];
  const float* gb  = (const float*)d_in[2];
  const float* w   = (const float*)d_in[3];
  const float* bia = (const float*)d_in[4];
  float* out = (float*)d_out;

  char* ws = (char*)d_ws;
  float*          logits_t = (float*)(ws + 0x0);        // 512 KB
  float*          vals     = (float*)(ws + 0x80000);    // 128 KB
  int*            idxb     = (int*)(ws + 0xA0000);      // 128 KB
  int*            cnt      = (int*)(ws + 0xC0000);      // 32 KB
  int*            hslot    = (int*)(ws + 0xC8000);      // 512 KB
  unsigned short* xbf      = (unsigned short*)(ws + 0x148000);    // 16 MB
  unsigned short* wtb      = (unsigned short*)(ws + 0x1148000);   // 32 MB
  unsigned short* tmp      = (unsigned short*)(ws + 0x3148000);   // 64 MB

  hipMemsetAsync(cnt, 0, B_NUM * S_DIM * sizeof(int), stream);

  prep_kernel<<<dim3(4096 + 2048), dim3(256), 0, stream>>>(w, wtb, x, gw, gb, logits_t, xbf);
  topk_kernel<<<dim3(B_NUM * E_NUM), dim3(256), 0, stream>>>(logits_t, vals, idxb, cnt, hslot);
  moe_gemm_kernel<<<dim3(512), dim3(512), 0, stream>>>(xbf, wtb, idxb, vals, bia, tmp);
  reduce_kernel<<<dim3(B_NUM * S_DIM), dim3(256), 0, stream>>>(tmp, cnt, hslot, out);
}

// Round 5
// 183.755 us; speedup vs baseline: 1.7366x; 1.1779x over previous
//
#include <hip/hip_runtime.h>

#define B_NUM 4
#define S_DIM 2048
#define D_DIM 1024
#define O_DIM 1024
#define E_NUM 16
#define K_SEL 512

typedef __attribute__((ext_vector_type(4))) float f32x4;
typedef __attribute__((ext_vector_type(8))) short s16x8;

__device__ __forceinline__ unsigned short f2b(float f) {
  union { float f; unsigned int u; } c; c.f = f;
  unsigned int u = c.u;
  u += 0x7fffu + ((u >> 16) & 1u);   // RNE to bf16
  return (unsigned short)(u >> 16);
}
__device__ __forceinline__ float b2f(unsigned short h) {
  union { unsigned int u; float f; } c; c.u = (unsigned int)h << 16; return c.f;
}

// ---------------- gw[d][e] -> gwT[e][d] (64 KB, coalesced writes) ----------------
__global__ __launch_bounds__(256) void gwt_kernel(const float* __restrict__ gw,
                                                  float* __restrict__ gwt) {
  int i = blockIdx.x * 256 + threadIdx.x;   // 16384 elements
  int e = i >> 10, d = i & 1023;
  gwt[i] = gw[d * E_NUM + e];
}

// ---------------- fused prep: blocks [0,4096) transpose w; [4096,6144) gate+convert ----------------
__global__ __launch_bounds__(256) void prep_kernel(const float* __restrict__ w,
                                                   unsigned short* __restrict__ wt,
                                                   const float* __restrict__ x,
                                                   const float* __restrict__ gwt,
                                                   const float* __restrict__ gb,
                                                   float* __restrict__ logits_t,
                                                   unsigned short* __restrict__ xb) {
  if (blockIdx.x < 4096) {
    // ---- transpose w[e][d][o] -> wt[e][o][d] bf16, 64x64 tile ----
    __shared__ float tile[64][65];
    int bx = blockIdx.x;
    int e = bx >> 8, d0 = ((bx >> 4) & 15) * 64, o0 = (bx & 15) * 64;
    int tx = threadIdx.x & 15, ty = threadIdx.x >> 4;
    const float* wbase = w + (size_t)e * D_DIM * O_DIM;
#pragma unroll
    for (int r = 0; r < 4; ++r) {
      int row = r * 16 + ty;
      float4 v = *reinterpret_cast<const float4*>(&wbase[(size_t)(d0 + row) * O_DIM + o0 + tx * 4]);
      tile[row][tx * 4 + 0] = v.x; tile[row][tx * 4 + 1] = v.y;
      tile[row][tx * 4 + 2] = v.z; tile[row][tx * 4 + 3] = v.w;
    }
    __syncthreads();
    unsigned short* wtb = wt + (size_t)e * O_DIM * D_DIM;
#pragma unroll
    for (int r = 0; r < 4; ++r) {
      int orow = r * 16 + ty;
      ushort4 u;
      u.x = f2b(tile[tx * 4 + 0][orow]);
      u.y = f2b(tile[tx * 4 + 1][orow]);
      u.z = f2b(tile[tx * 4 + 2][orow]);
      u.w = f2b(tile[tx * 4 + 3][orow]);
      *reinterpret_cast<ushort4*>(&wtb[(size_t)(o0 + orow) * D_DIM + d0 + tx * 4]) = u;
    }
  } else {
    // ---- gate logits (fp32, coalesced via gwT) + x -> bf16 ----
    int wave = ((blockIdx.x - 4096) * 256 + threadIdx.x) >> 6;  // token index
    int ln = threadIdx.x & 63;
    int bi = wave / S_DIM, s = wave % S_DIM;
    const float* xr = x + (size_t)wave * D_DIM;
    unsigned short* xbr = xb + (size_t)wave * D_DIM;
    float acc[E_NUM];
#pragma unroll
    for (int e = 0; e < E_NUM; ++e) acc[e] = 0.f;
#pragma unroll
    for (int it = 0; it < 4; ++it) {
      int d0 = it * 256 + ln * 4;
      float4 xv = *reinterpret_cast<const float4*>(&xr[d0]);
      ushort4 u;
      u.x = f2b(xv.x); u.y = f2b(xv.y); u.z = f2b(xv.z); u.w = f2b(xv.w);
      *reinterpret_cast<ushort4*>(&xbr[d0]) = u;
#pragma unroll
      for (int e = 0; e < E_NUM; ++e) {
        float4 gv = *reinterpret_cast<const float4*>(&gwt[e * D_DIM + d0]);
        acc[e] = fmaf(xv.x, gv.x, fmaf(xv.y, gv.y,
                 fmaf(xv.z, gv.z, fmaf(xv.w, gv.w, acc[e]))));
      }
    }
    float myv = 0.f;
#pragma unroll
    for (int e = 0; e < E_NUM; ++e) {
      float v = acc[e];
#pragma unroll
      for (int o = 32; o > 0; o >>= 1) v += __shfl_xor(v, o);
      if (ln == e) myv = v;
    }
    if (ln < E_NUM)
      logits_t[((size_t)bi * E_NUM + ln) * S_DIM + s] = myv + gb[ln];
  }
}

// ---------------- per-(b,e): softmax consts + radix-select top-512 + inverted index ----------------
__global__ __launch_bounds__(256) void topk_kernel(const float* __restrict__ logits_t,
                                                   float* __restrict__ vals, int* __restrict__ idxb,
                                                   int* __restrict__ cnt, int* __restrict__ hslot) {
  __shared__ float red[256];
  __shared__ int hist[256];
  __shared__ unsigned sh_prefix;
  __shared__ int sh_need;
  __shared__ int outc;
  __shared__ unsigned tiebm[64];
  __shared__ int wordpfx[64];

  const int row = blockIdx.x;           // b*E + e
  const int bi = row >> 4, ei = row & 15;
  const int tid = threadIdx.x;
  const float* lp = logits_t + (size_t)row * S_DIM;

  float v[8];
  unsigned key[8];
  float lmax = -1e30f;
#pragma unroll
  for (int j = 0; j < 8; ++j) {
    float f = lp[j * 256 + tid];
    v[j] = f;
    unsigned u = __float_as_uint(f);
    key[j] = (u & 0x80000000u) ? ~u : (u | 0x80000000u);  // ascending uint == ascending float
    lmax = fmaxf(lmax, f);
  }
  red[tid] = lmax; __syncthreads();
  for (int o = 128; o > 0; o >>= 1) {
    if (tid < o) red[tid] = fmaxf(red[tid], red[tid + o]);
    __syncthreads();
  }
  const float mx = red[0]; __syncthreads();
  float lsum = 0.f;
#pragma unroll
  for (int j = 0; j < 8; ++j) lsum += expf(v[j] - mx);
  red[tid] = lsum; __syncthreads();
  for (int o = 128; o > 0; o >>= 1) {
    if (tid < o) red[tid] += red[tid + o];
    __syncthreads();
  }
  const float Z = red[0];

  unsigned prefix = 0;
  int need = K_SEL;
#pragma unroll
  for (int pass = 0; pass < 4; ++pass) {
    const int shift = 24 - pass * 8;
    __syncthreads();
    hist[tid] = 0;
    __syncthreads();
    const unsigned pmask = (pass == 0) ? 0u : (0xFFFFFFFFu << (shift + 8));
#pragma unroll
    for (int j = 0; j < 8; ++j)
      if ((key[j] & pmask) == prefix) atomicAdd(&hist[(key[j] >> shift) & 0xFF], 1);
    __syncthreads();
    if (tid == 0) {
      int cum = 0, bsel = 0;
      for (int b = 255; b >= 0; --b) {
        cum += hist[b];
        if (cum >= need) { bsel = b; break; }
      }
      sh_prefix = prefix | ((unsigned)bsel << shift);
      sh_need = need - (cum - hist[bsel]);
    }
    __syncthreads();
    prefix = sh_prefix;
    need = sh_need;
  }
  const unsigned T = prefix;
  const int need_rem = need;

  if (tid == 0) outc = 0;
  if (tid < 64) tiebm[tid] = 0;
  __syncthreads();

#pragma unroll
  for (int j = 0; j < 8; ++j) {
    const int s = j * 256 + tid;
    if (key[j] > T) {
      int p = atomicAdd(&outc, 1);
      vals[row * K_SEL + p] = expf(v[j] - mx) / Z;
      idxb[row * K_SEL + p] = s;
      int hp = atomicAdd(&cnt[bi * S_DIM + s], 1);
      hslot[(bi * S_DIM + s) * 16 + hp] = ei * K_SEL + p;
    } else if (key[j] == T) {
      atomicOr(&tiebm[s >> 5], 1u << (s & 31));
    }
  }
  __syncthreads();
  if (tid == 0) {
    int c = 0;
    for (int w2 = 0; w2 < 64; ++w2) { wordpfx[w2] = c; c += __popc(tiebm[w2]); }
  }
  __syncthreads();
  if (tid < 64) {
    unsigned m = tiebm[tid];
    int base = wordpfx[tid];
    const int p0 = outc;
    while (m) {
      int bit = __ffs(m) - 1;
      m &= m - 1;
      if (base < need_rem) {
        int s = tid * 32 + bit;
        int p = p0 + base;
        vals[row * K_SEL + p] = expf(lp[s] - mx) / Z;
        idxb[row * K_SEL + p] = s;
        int hp = atomicAdd(&cnt[bi * S_DIM + s], 1);
        hslot[(bi * S_DIM + s) * 16 + hp] = ei * K_SEL + p;
      }
      base++;
    }
  }
}

// ---------------- grouped GEMM: 256x256, BK=64, 8 waves, phased schedule, counted vmcnt ----------------
__global__ __launch_bounds__(512, 1) void moe_gemm_kernel(
    const unsigned short* __restrict__ xb,   // [B,S,D] bf16
    const unsigned short* __restrict__ wt,   // [E,O,D] bf16
    const int* __restrict__ idxbuf,          // [B*E,K]
    const float* __restrict__ valbuf,        // [B*E,K]
    const float* __restrict__ bias,          // [E]
    unsigned short* __restrict__ tmp)        // [B*E,K,O] bf16
{
  __shared__ __align__(16) unsigned short lA[2][256 * 64];
  __shared__ __align__(16) unsigned short lB[2][256 * 64];

  const int tid = threadIdx.x;
  const int wv = tid >> 6, ln = tid & 63;
  const int wm = wv >> 2, wn = wv & 3;

  const int bid = blockIdx.x;
  const int swz = (bid & 7) * 64 + (bid >> 3);   // XCD-chunked (512 % 8 == 0, bijective)
  const int n0 = (swz & 3) * 256;
  const int m0 = ((swz >> 2) & 1) * 256;
  const int grp = swz >> 3;                // b*E + e
  const int bi = grp >> 4, ei = grp & 15;

  const unsigned short* aSrcP[4];
  const unsigned short* bSrcP[4];
  const int lslot = (ln & 7) ^ (ln >> 3);
#pragma unroll
  for (int s = 0; s < 4; ++s) {
    const int r = s * 64 + wv * 8 + (ln >> 3);
    const int tok = idxbuf[grp * K_SEL + m0 + r];
    aSrcP[s] = xb + ((size_t)bi * S_DIM + tok) * D_DIM + lslot * 8;
    bSrcP[s] = wt + ((size_t)ei * O_DIM + (n0 + r)) * D_DIM + lslot * 8;
  }

  const unsigned rowA = wm * 128 + (ln & 15);
  const unsigned rowB = wn * 64 + (ln & 15);
  const unsigned phys0 = (ln >> 4) ^ (ln & 7);
  const unsigned phys1 = (4 + (ln >> 4)) ^ (ln & 7);

  f32x4 acc[8][4];
  f32x4 zero4 = {0.f, 0.f, 0.f, 0.f};
#pragma unroll
  for (int i = 0; i < 8; ++i)
#pragma unroll
    for (int j = 0; j < 4; ++j) acc[i][j] = zero4;

  s16x8 bfr[4][2];

#define GLD(dst, src)                                                          \
  __builtin_amdgcn_global_load_lds(                                            \
      (const __attribute__((address_space(1))) void*)(src),                    \
      (__attribute__((address_space(3))) void*)(dst), 16, 0, 0)
#define VMW(N) asm volatile("s_waitcnt vmcnt(" #N ")" ::: "memory")
#define LGKM0 asm volatile("s_waitcnt lgkmcnt(0)" ::: "memory")
#define DS_A(CUR, i, PH) (*(const s16x8*)&lA[CUR][rowA * 64u + (i) * 1024u + (PH) * 8u])
#define DS_B(CUR, j, PH) (*(const s16x8*)&lB[CUR][rowB * 64u + (j) * 1024u + (PH) * 8u])

#define MFMA16(P)                                                              \
  __builtin_amdgcn_s_setprio(1);                                               \
  _Pragma("unroll") for (int jj = 0; jj < 4; ++jj) {                           \
    acc[2*(P)][jj]   = __builtin_amdgcn_mfma_f32_16x16x32_bf16(aL0, bfr[jj][0], acc[2*(P)][jj], 0, 0, 0);   \
    acc[2*(P)][jj]   = __builtin_amdgcn_mfma_f32_16x16x32_bf16(aL1, bfr[jj][1], acc[2*(P)][jj], 0, 0, 0);   \
    acc[2*(P)+1][jj] = __builtin_amdgcn_mfma_f32_16x16x32_bf16(aH0, bfr[jj][0], acc[2*(P)+1][jj], 0, 0, 0); \
    acc[2*(P)+1][jj] = __builtin_amdgcn_mfma_f32_16x16x32_bf16(aH1, bfr[jj][1], acc[2*(P)+1][jj], 0, 0, 0); \
  }                                                                            \
  __builtin_amdgcn_s_setprio(0);

#define KTILE(CUR, NXT, KT, DOSTAGE, VM1, VM3)                                 \
  {                                                                            \
    { /* phase 0 */                                                            \
      _Pragma("unroll") for (int jj = 0; jj < 4; ++jj) {                       \
        bfr[jj][0] = DS_B(CUR, jj, phys0);                                     \
        bfr[jj][1] = DS_B(CUR, jj, phys1);                                     \
      }                                                                        \
      s16x8 aL0 = DS_A(CUR, 0, phys0), aL1 = DS_A(CUR, 0, phys1);              \
      s16x8 aH0 = DS_A(CUR, 1, phys0), aH1 = DS_A(CUR, 1, phys1);              \
      if (DOSTAGE) {                                                           \
        GLD(&lB[NXT][(wv * 8) * 64],        bSrcP[0] + (KT) * 64);             \
        GLD(&lB[NXT][(64 + wv * 8) * 64],   bSrcP[1] + (KT) * 64);             \
      }                                                                        \
      __builtin_amdgcn_s_barrier();                                            \
      LGKM0; __builtin_amdgcn_sched_barrier(0);                                \
      MFMA16(0);                                                               \
      __builtin_amdgcn_s_barrier();                                            \
    }                                                                          \
    { /* phase 1 */                                                            \
      s16x8 aL0 = DS_A(CUR, 2, phys0), aL1 = DS_A(CUR, 2, phys1);              \
      s16x8 aH0 = DS_A(CUR, 3, phys0), aH1 = DS_A(CUR, 3, phys1);              \
      if (DOSTAGE) {                                                           \
        GLD(&lB[NXT][(128 + wv * 8) * 64],  bSrcP[2] + (KT) * 64);             \
        GLD(&lB[NXT][(192 + wv * 8) * 64],  bSrcP[3] + (KT) * 64);             \
      }                                                                        \
      VM1;                                                                     \
      __builtin_amdgcn_s_barrier();                                            \
      LGKM0; __builtin_amdgcn_sched_barrier(0);                                \
      MFMA16(1);                                                               \
      __builtin_amdgcn_s_barrier();                                            \
    }                                                                          \
    { /* phase 2 */                                                            \
      s16x8 aL0 = DS_A(CUR, 4, phys0), aL1 = DS_A(CUR, 4, phys1);              \
      s16x8 aH0 = DS_A(CUR, 5, phys0), aH1 = DS_A(CUR, 5, phys1);              \
      if (DOSTAGE) {                                                           \
        GLD(&lA[NXT][(wv * 8) * 64],        aSrcP[0] + (KT) * 64);             \
        GLD(&lA[NXT][(128 + wv * 8) * 64],  aSrcP[2] + (KT) * 64);             \
      }                                                                        \
      __builtin_amdgcn_s_barrier();                                            \
      LGKM0; __builtin_amdgcn_sched_barrier(0);                                \
      MFMA16(2);                                                               \
      __builtin_amdgcn_s_barrier();                                            \
    }                                                                          \
    { /* phase 3 */                                                            \
      s16x8 aL0 = DS_A(CUR, 6, phys0), aL1 = DS_A(CUR, 6, phys1);              \
      s16x8 aH0 = DS_A(CUR, 7, phys0), aH1 = DS_A(CUR, 7, phys1);              \
      if (DOSTAGE) {                                                           \
        GLD(&lA[NXT][(64 + wv * 8) * 64],   aSrcP[1] + (KT) * 64);             \
        GLD(&lA[NXT][(192 + wv * 8) * 64],  aSrcP[3] + (KT) * 64);             \
      }                                                                        \
      VM3;                                                                     \
      __builtin_amdgcn_s_barrier();                                            \
      LGKM0; __builtin_amdgcn_sched_barrier(0);                                \
      MFMA16(3);                                                               \
      __builtin_amdgcn_s_barrier();                                            \
    }                                                                          \
  }

  GLD(&lB[0][(wv * 8) * 64],        bSrcP[0]);
  GLD(&lB[0][(64 + wv * 8) * 64],   bSrcP[1]);
  GLD(&lB[0][(128 + wv * 8) * 64],  bSrcP[2]);
  GLD(&lB[0][(192 + wv * 8) * 64],  bSrcP[3]);
  GLD(&lA[0][(wv * 8) * 64],        aSrcP[0]);
  GLD(&lA[0][(128 + wv * 8) * 64],  aSrcP[2]);
  GLD(&lA[0][(64 + wv * 8) * 64],   aSrcP[1]);
  GLD(&lA[0][(192 + wv * 8) * 64],  aSrcP[3]);
  VMW(0);
  __builtin_amdgcn_s_barrier();

  for (int t = 0; t < 14; t += 2) {
    KTILE(0, 1, t + 1, 1, VMW(4), VMW(2));
    KTILE(1, 0, t + 2, 1, VMW(4), VMW(2));
  }
  KTILE(0, 1, 15, 1, VMW(4), VMW(2));
  KTILE(1, 0, 0, 0, VMW(0), ((void)0));

  const float be = bias[ei];
#pragma unroll
  for (int i = 0; i < 8; ++i) {
#pragma unroll
    for (int r = 0; r < 4; ++r) {
      const int krow = m0 + wm * 128 + i * 16 + (ln >> 4) * 4 + r;
      const float inv = 1.0f / valbuf[grp * K_SEL + krow];
      unsigned short* trow = tmp + ((size_t)grp * K_SEL + krow) * O_DIM;
#pragma unroll
      for (int j = 0; j < 4; ++j) {
        const int col = n0 + wn * 64 + j * 16 + (ln & 15);
        trow[col] = f2b((acc[i][j][r] + be) * inv);
      }
    }
  }
#undef GLD
#undef VMW
#undef LGKM0
#undef DS_A
#undef DS_B
#undef MFMA16
#undef KTILE
}

// ---------------- per-token gather-reduce ----------------
__global__ __launch_bounds__(256) void reduce_kernel(const unsigned short* __restrict__ tmp,
                                                     const int* __restrict__ cnt,
                                                     const int* __restrict__ hslot,
                                                     float* __restrict__ out) {
  const int t = blockIdx.x;        // b*S + s
  const int bi = t >> 11;
  const int tid = threadIdx.x;
  const int n = cnt[t];
  float4 a = {0.f, 0.f, 0.f, 0.f};
  for (int h = 0; h < n; ++h) {
    const int u = hslot[t * 16 + h];  // e*K + p
    const unsigned short* tr = tmp + ((size_t)bi * E_NUM * K_SEL + u) * O_DIM + tid * 4;
    ushort4 q = *reinterpret_cast<const ushort4*>(tr);
    a.x += b2f(q.x); a.y += b2f(q.y); a.z += b2f(q.z); a.w += b2f(q.w);
  }
  *reinterpret_cast<float4*>(&out[(size_t)t * O_DIM + tid * 4]) = a;
}

extern "C" void kernel_launch(void* const* d_in, const int* in_sizes, int n_in,
                              void* d_out, int out_size, void* d_ws, size_t ws_size,
                              hipStream_t stream) {
  const float* x   = (const float*)d_in[0];
  const float* gw  = (const float*)d_in[1];
  const float* gb  = (const float*)d_in[2];
  const float* w   = (const float*)d_in[3];
  const float* bia = (const float*)d_in[4];
  float* out = (float*)d_out;

  char* ws = (char*)d_ws;
  float*          logits_t = (float*)(ws + 0x0);        // 512 KB
  float*          vals     = (float*)(ws + 0x80000);    // 128 KB
  int*            idxb     = (int*)(ws + 0xA0000);      // 128 KB
  int*            cnt      = (int*)(ws + 0xC0000);      // 32 KB
  int*            hslot    = (int*)(ws + 0xC8000);      // 512 KB
  unsigned short* xbf      = (unsigned short*)(ws + 0x148000);    // 16 MB
  unsigned short* wtb      = (unsigned short*)(ws + 0x1148000);   // 32 MB
  unsigned short* tmp      = (unsigned short*)(ws + 0x3148000);   // 64 MB
  float*          gwt      = (float*)(ws + 0x7148000);            // 64 KB

  hipMemsetAsync(cnt, 0, B_NUM * S_DIM * sizeof(int), stream);

  gwt_kernel<<<dim3(64), dim3(256), 0, stream>>>(gw, gwt);
  prep_kernel<<<dim3(4096 + 2048), dim3(256), 0, stream>>>(w, wtb, x, gwt, gb, logits_t, xbf);
  topk_kernel<<<dim3(B_NUM * E_NUM), dim3(256), 0, stream>>>(logits_t, vals, idxb, cnt, hslot);
  moe_gemm_kernel<<<dim3(512), dim3(512), 0, stream>>>(xbf, wtb, idxb, vals, bia, tmp);
  reduce_kernel<<<dim3(B_NUM * S_DIM), dim3(256), 0, stream>>>(tmp, cnt, hslot, out);
}